// Round 9
// baseline (256.885 us; speedup 1.0000x reference)
//
#include <hip/hip_runtime.h>
#include <hip/hip_cooperative_groups.h>

namespace cg = cooperative_groups;

#define IN_FEAT 4096
#define OUT_FEAT 4096
#define RANK 64
#define NROWS 16384
#define TM 32              // rows per block
#define BT 512             // threads per block (8 waves)
#define KC2 256            // K-chunk (f32 elems) staged per buffer
#define SXS 264            // xs inner stride (f16): 256 + 8 pad
#define XP_STRIDE 72
#define KC 256             // fallback kernel chunk
#define WA_STRIDE 264

typedef _Float16 half_t;
typedef _Float16 f16x4 __attribute__((ext_vector_type(4)));
typedef _Float16 f16x8 __attribute__((ext_vector_type(8)));
typedef float f32x4 __attribute__((ext_vector_type(4)));

// 2:4 soft-threshold one aligned group of 4, scale, cast to f16 (RNE).
__device__ __forceinline__ f16x4 thr4(float4 v, float s) {
    float a0 = fabsf(v.x), a1 = fabsf(v.y), a2 = fabsf(v.z), a3 = fabsf(v.w);
    float lo1 = fminf(a0, a1), hi1 = fmaxf(a0, a1);
    float lo2 = fminf(a2, a3), hi2 = fmaxf(a2, a3);
    float t = fminf(fmaxf(lo1, lo2), fminf(hi1, hi2));  // 2nd-smallest = 3rd-largest
    f16x4 r;
    r[0] = (half_t)(copysignf(fmaxf(a0 - t, 0.0f), v.x) * s);
    r[1] = (half_t)(copysignf(fmaxf(a1 - t, 0.0f), v.y) * s);
    r[2] = (half_t)(copysignf(fmaxf(a2 - t, 0.0f), v.z) * s);
    r[3] = (half_t)(copysignf(fmaxf(a3 - t, 0.0f), v.w) * s);
    return r;
}

__device__ __forceinline__ f16x4 cvt4(f32x4 v) {
    f16x4 h;
    h[0] = (half_t)v[0]; h[1] = (half_t)v[1];
    h[2] = (half_t)v[2]; h[3] = (half_t)v[3];
    return h;
}

// ================= cooperative single-launch kernel =========================
// grid = 512 blocks x 512 threads (8 waves). Plain __launch_bounds__(512) —
// the exact contract that launched successfully in rounds 6-7 (VGPR stays
// low; LDS 38.4 KB < round 7's 39.4 KB, so >=2 blocks/CU capacity holds).
// Phase 0: weight prep -> ws. grid.sync.
// Phase A: xp = f16(x)@wA'. K staged in double-buffered LDS chunks; loads for
//          chunk c+1 (4 x dwordx4/thread, contiguous 256B/instr per wave) fly
//          during chunk c's MFMAs. Waves split columns: wave (stripe,quad)
//          owns rows stripe*16+.., cols quad*16+.., full K.
// Phase B: out = xp@wB'^T + bias, cols quartered across wave pairs.
__global__ __launch_bounds__(BT) void coop_kernel(
    const float* __restrict__ x, const float* __restrict__ wA,
    const float* __restrict__ wB, const float* __restrict__ bias,
    const float* __restrict__ scaleA, const float* __restrict__ scaleB,
    float* __restrict__ out, half_t* __restrict__ wAT, half_t* __restrict__ wBh)
{
    __shared__ __align__(16) half_t xs[2][TM][SXS];        // 33.8 KB x-tile dbuf
    __shared__ __align__(16) half_t xp[TM][XP_STRIDE];     // 4.6 KB

    int tid = threadIdx.x;
    int bid = blockIdx.x;

    // ---- Phase 0: prep. 131072 group-tasks over 262144 threads -------------
    {
        int id = bid * BT + tid;
        if (id < 131072) {
            bool isB = id >= 65536;
            int gid = id & 65535;
            int row = gid >> 4;                    // 0..4095
            int gq  = gid & 15;                    // group-of-4 along rank
            const float* src = (isB ? wB : wA) + (size_t)row * RANK + gq * 4;
            float s = isB ? scaleB[0] : scaleA[0];
            f16x4 h = thr4(*(const float4*)src, s);
            if (!isB) {
                int c = gq * 4;
                wAT[(size_t)(c + 0) * IN_FEAT + row] = h[0];
                wAT[(size_t)(c + 1) * IN_FEAT + row] = h[1];
                wAT[(size_t)(c + 2) * IN_FEAT + row] = h[2];
                wAT[(size_t)(c + 3) * IN_FEAT + row] = h[3];
            } else {
                *(f16x4*)(wBh + (size_t)row * RANK + gq * 4) = h;
            }
        }
    }
    cg::this_grid().sync();

    int wave = tid >> 6;                           // 0..7
    int lane = tid & 63;
    int l16  = lane & 15;
    int g    = lane >> 4;
    int rowbase = bid * TM;
    int stripe  = wave & 1;                        // 16-row half
    int quad    = wave >> 1;                       // col quarter (A and B)

    // staging role: thread (srow, sseg); wave loads 4 rows x 256B contiguous/instr
    int srow = tid >> 4;                           // 0..31
    int sseg = tid & 15;                           // 0..15
    const float* srcrow = x + (size_t)(rowbase + srow) * IN_FEAT + sseg * 4;

    f32x4 ld0, ld1, ld2, ld3;

    // ---- Phase A ------------------------------------------------------------
    {
        // prologue: stage chunk 0
        {
            const f32x4* p = (const f32x4*)(srcrow);
            ld0 = p[0]; ld1 = p[16]; ld2 = p[32]; ld3 = p[48];
            half_t* dst = &xs[0][srow][sseg * 4];
            *(f16x4*)(dst +   0) = cvt4(ld0);
            *(f16x4*)(dst +  64) = cvt4(ld1);
            *(f16x4*)(dst + 128) = cvt4(ld2);
            *(f16x4*)(dst + 192) = cvt4(ld3);
        }
        __syncthreads();

        f32x4 acc = {0, 0, 0, 0};
        const half_t* wcol = wAT + (size_t)(quad * 16 + l16) * IN_FEAT;
        const half_t* arow = &xs[0][stripe * 16 + l16][0];
        const int xsstep = TM * SXS;               // f16 elems between buffers

        for (int c = 0; c < IN_FEAT / KC2; ++c) {
            if (c + 1 < IN_FEAT / KC2) {           // issue next chunk's loads
                const f32x4* p = (const f32x4*)(srcrow + (c + 1) * KC2);
                ld0 = p[0]; ld1 = p[16]; ld2 = p[32]; ld3 = p[48];
            }
            int kb = c * KC2;
            const half_t* ar = arow + (c & 1) * xsstep;
#pragma unroll
            for (int k8 = 0; k8 < KC2 / 32; ++k8) {        // 8 MFMAs per chunk
                f16x8 a = *(const f16x8*)(ar + k8 * 32 + 8 * g);
                f16x8 b = *(const f16x8*)(wcol + kb + k8 * 32 + 8 * g);
                acc = __builtin_amdgcn_mfma_f32_16x16x32_f16(a, b, acc, 0, 0, 0);
            }
            if (c + 1 < IN_FEAT / KC2) {           // commit to the other buffer
                half_t* dst = &xs[(c + 1) & 1][srow][sseg * 4];
                *(f16x4*)(dst +   0) = cvt4(ld0);
                *(f16x4*)(dst +  64) = cvt4(ld1);
                *(f16x4*)(dst + 128) = cvt4(ld2);
                *(f16x4*)(dst + 192) = cvt4(ld3);
            }
            __syncthreads();
        }

        // full-K f32 acc -> f16 xp (ref: x_proj f32 cast to f16 for GEMM2)
        // C/D: col = lane&15, row = 4*(lane>>4)+reg
#pragma unroll
        for (int r = 0; r < 4; ++r)
            xp[stripe * 16 + 4 * g + r][quad * 16 + l16] = (half_t)acc[r];
    }
    __syncthreads();

    // ---- Phase B: out = xp @ wB'^T + bias ----------------------------------
    {
        const half_t* xprow = &xp[stripe * 16 + l16][0];
        f16x8 a0 = *(const f16x8*)(xprow + 8 * g);
        f16x8 a1 = *(const f16x8*)(xprow + 32 + 8 * g);

        int cb0 = quad * (OUT_FEAT / 4);
#pragma unroll 2
        for (int cb = cb0; cb < cb0 + OUT_FEAT / 4; cb += 64) {
#pragma unroll
            for (int f = 0; f < 4; ++f) {
                int col = cb + 16 * f + l16;
                const half_t* wp = wBh + (size_t)col * RANK;   // B[k][col] = wB'[col][k]
                f16x8 b0 = *(const f16x8*)(wp + 8 * g);
                f16x8 b1 = *(const f16x8*)(wp + 32 + 8 * g);
                f32x4 acc2 = {0, 0, 0, 0};
                acc2 = __builtin_amdgcn_mfma_f32_16x16x32_f16(a0, b0, acc2, 0, 0, 0);
                acc2 = __builtin_amdgcn_mfma_f32_16x16x32_f16(a1, b1, acc2, 0, 0, 0);
                float bv = bias[col];
#pragma unroll
                for (int r = 0; r < 4; ++r)
                    out[(size_t)(rowbase + stripe * 16 + 4 * g + r) * OUT_FEAT + col] = acc2[r] + bv;
            }
        }
    }
}

// ===================== fallback: zero-ws fused (round-4, passing) ===========
__global__ __launch_bounds__(256) void fused_kernel(
    const float* __restrict__ x, const float* __restrict__ wA,
    const float* __restrict__ wB, const float* __restrict__ bias,
    const float* __restrict__ scaleA, const float* __restrict__ scaleB,
    float* __restrict__ out)
{
    __shared__ __align__(16) half_t wAsT[RANK][WA_STRIDE];
    __shared__ float xp_part[2][TM][XP_STRIDE];
    __shared__ __align__(16) half_t xp[TM][XP_STRIDE];

    int tid  = threadIdx.x;
    int wave = tid >> 6;
    int lane = tid & 63;
    int l16  = lane & 15;
    int g    = lane >> 4;
    int rowbase = blockIdx.x * TM;
    int stripe  = wave & 1;
    int ks      = wave >> 1;

    float sA = scaleA[0];
    float sB = scaleB[0];

    const float* xrow = x + (size_t)(rowbase + stripe * 16 + l16) * IN_FEAT;
    f32x4 acc[4] = {f32x4{0,0,0,0}, f32x4{0,0,0,0}, f32x4{0,0,0,0}, f32x4{0,0,0,0}};

    for (int chunk = 0; chunk < IN_FEAT / KC; ++chunk) {
        int k0 = chunk * KC;
#pragma unroll
        for (int pp = 0; pp < 2; ++pp) {
            int p = tid + pp * 256;
            int q = p & 15;
            int r = p >> 4;
            f16x8 vc0, vc1, vc2, vc3;
#pragma unroll
            for (int i = 0; i < 8; ++i) {
                float4 v = *(const float4*)(wA + (size_t)(k0 + 8 * r + i) * RANK + 4 * q);
                f16x4 h = thr4(v, sA);
                vc0[i] = h[0]; vc1[i] = h[1]; vc2[i] = h[2]; vc3[i] = h[3];
            }
            *(f16x8*)&wAsT[4 * q + 0][8 * r] = vc0;
            *(f16x8*)&wAsT[4 * q + 1][8 * r] = vc1;
            *(f16x8*)&wAsT[4 * q + 2][8 * r] = vc2;
            *(f16x8*)&wAsT[4 * q + 3][8 * r] = vc3;
        }
        __syncthreads();

#pragma unroll
        for (int it = 0; it < 4; ++it) {
            int kloc = ks * 128 + it * 32;
            float4 xa = *(const float4*)(xrow + k0 + kloc + 8 * g);
            float4 xb = *(const float4*)(xrow + k0 + kloc + 8 * g + 4);
            f16x8 a;
            a[0] = (half_t)xa.x; a[1] = (half_t)xa.y; a[2] = (half_t)xa.z; a[3] = (half_t)xa.w;
            a[4] = (half_t)xb.x; a[5] = (half_t)xb.y; a[6] = (half_t)xb.z; a[7] = (half_t)xb.w;
#pragma unroll
            for (int f = 0; f < 4; ++f) {
                f16x8 b = *(const f16x8*)&wAsT[16 * f + l16][kloc + 8 * g];
                acc[f] = __builtin_amdgcn_mfma_f32_16x16x32_f16(a, b, acc[f], 0, 0, 0);
            }
        }
        __syncthreads();
    }

#pragma unroll
    for (int f = 0; f < 4; ++f)
#pragma unroll
        for (int r = 0; r < 4; ++r)
            xp_part[ks][stripe * 16 + 4 * g + r][16 * f + l16] = acc[f][r];
    __syncthreads();

#pragma unroll
    for (int i = 0; i < (TM * RANK) / 256; ++i) {
        int e = i * 256 + tid;
        int r = e >> 6, c = e & 63;
        xp[r][c] = (half_t)(xp_part[0][r][c] + xp_part[1][r][c]);
    }
    __syncthreads();

    {
        const half_t* xprow = &xp[stripe * 16 + l16][0];
        f16x8 a0 = *(const f16x8*)(xprow + 8 * g);
        f16x8 a1 = *(const f16x8*)(xprow + 32 + 8 * g);

        int cb0 = ks * (OUT_FEAT / 2);
        for (int cb = cb0; cb < cb0 + OUT_FEAT / 2; cb += 16) {
            int col = cb + l16;
            const float* wp = wB + (size_t)col * RANK;
            float4 w00 = *(const float4*)(wp + 8 * g);
            float4 w01 = *(const float4*)(wp + 8 * g + 4);
            float4 w10 = *(const float4*)(wp + 32 + 8 * g);
            float4 w11 = *(const float4*)(wp + 32 + 8 * g + 4);
            f16x4 b00 = thr4(w00, sB), b01 = thr4(w01, sB);
            f16x4 b10 = thr4(w10, sB), b11 = thr4(w11, sB);
            f16x8 b0, b1;
            b0[0]=b00[0]; b0[1]=b00[1]; b0[2]=b00[2]; b0[3]=b00[3];
            b0[4]=b01[0]; b0[5]=b01[1]; b0[6]=b01[2]; b0[7]=b01[3];
            b1[0]=b10[0]; b1[1]=b10[1]; b1[2]=b10[2]; b1[3]=b10[3];
            b1[4]=b11[0]; b1[5]=b11[1]; b1[6]=b11[2]; b1[7]=b11[3];

            f32x4 acc2 = {0, 0, 0, 0};
            acc2 = __builtin_amdgcn_mfma_f32_16x16x32_f16(a0, b0, acc2, 0, 0, 0);
            acc2 = __builtin_amdgcn_mfma_f32_16x16x32_f16(a1, b1, acc2, 0, 0, 0);
            float bv = bias[col];
#pragma unroll
            for (int r = 0; r < 4; ++r)
                out[(size_t)(rowbase + stripe * 16 + 4 * g + r) * OUT_FEAT + col] = acc2[r] + bv;
        }
    }
}

extern "C" void kernel_launch(void* const* d_in, const int* in_sizes, int n_in,
                              void* d_out, int out_size, void* d_ws, size_t ws_size,
                              hipStream_t stream) {
    const float* x      = (const float*)d_in[0];
    const float* wA     = (const float*)d_in[1];
    const float* wB     = (const float*)d_in[2];
    const float* bias   = (const float*)d_in[3];
    const float* scaleA = (const float*)d_in[4];
    const float* scaleB = (const float*)d_in[5];
    float* out = (float*)d_out;

    const size_t WS_NEED = (size_t)RANK * IN_FEAT * 2      // wAT 512 KB
                         + (size_t)OUT_FEAT * RANK * 2;    // wBh 512 KB

    bool launched = false;
    if (ws_size >= WS_NEED && d_ws != nullptr) {
        half_t* wAT = (half_t*)d_ws;
        half_t* wBh = wAT + (size_t)RANK * IN_FEAT;
        void* args[] = {(void*)&x, (void*)&wA, (void*)&wB, (void*)&bias,
                        (void*)&scaleA, (void*)&scaleB, (void*)&out,
                        (void*)&wAT, (void*)&wBh};
        hipError_t err = hipLaunchCooperativeKernel((void*)coop_kernel,
                                                    dim3(NROWS / TM), dim3(BT),
                                                    args, 0, stream);
        launched = (err == hipSuccess);
    }
    if (!launched) {
        fused_kernel<<<NROWS / TM, 256, 0, stream>>>(x, wA, wB, bias, scaleA, scaleB, out);
    }
}

// Round 10
// 212.113 us; speedup vs baseline: 1.2111x; 1.2111x over previous
//
#include <hip/hip_runtime.h>
#include <hip/hip_cooperative_groups.h>

namespace cg = cooperative_groups;

#define IN_FEAT 4096
#define OUT_FEAT 4096
#define RANK 64
#define NROWS 16384
#define TM 32              // rows per block
#define BT 512             // threads per block (8 waves)
#define KC2 256            // phase-A K-chunk (f32 elems)
#define SXS 264            // xs inner stride (f16)
#define CT 256             // phase-B col-tile
#define WBS 72             // wbs inner stride (f16): 64 + 8 pad, 144B (16B mult)
#define XP_STRIDE 72
#define KC 256             // fallback kernel chunk
#define WA_STRIDE 264

typedef _Float16 half_t;
typedef _Float16 f16x4 __attribute__((ext_vector_type(4)));
typedef _Float16 f16x8 __attribute__((ext_vector_type(8)));
typedef float f32x4 __attribute__((ext_vector_type(4)));

// 2:4 soft-threshold one aligned group of 4, scale, cast to f16 (RNE).
__device__ __forceinline__ f16x4 thr4(float4 v, float s) {
    float a0 = fabsf(v.x), a1 = fabsf(v.y), a2 = fabsf(v.z), a3 = fabsf(v.w);
    float lo1 = fminf(a0, a1), hi1 = fmaxf(a0, a1);
    float lo2 = fminf(a2, a3), hi2 = fmaxf(a2, a3);
    float t = fminf(fmaxf(lo1, lo2), fminf(hi1, hi2));  // 2nd-smallest = 3rd-largest
    f16x4 r;
    r[0] = (half_t)(copysignf(fmaxf(a0 - t, 0.0f), v.x) * s);
    r[1] = (half_t)(copysignf(fmaxf(a1 - t, 0.0f), v.y) * s);
    r[2] = (half_t)(copysignf(fmaxf(a2 - t, 0.0f), v.z) * s);
    r[3] = (half_t)(copysignf(fmaxf(a3 - t, 0.0f), v.w) * s);
    return r;
}

__device__ __forceinline__ f16x4 cvt4(f32x4 v) {
    f16x4 h;
    h[0] = (half_t)v[0]; h[1] = (half_t)v[1];
    h[2] = (half_t)v[2]; h[3] = (half_t)v[3];
    return h;
}

// ================= cooperative single-launch kernel =========================
// grid = 512 x 512 threads (8 waves), 76.5 KB LDS -> 2 blocks/CU.
// Phase 0: prep weights -> ws (coalesced v2). grid.sync.
// Phase A: xp = f16(x)@wA'. x double-buffered in LDS; all 8 wAT fragments
//          per chunk batched into registers (one L2 round-trip per chunk).
// Phase B: out = xp@wB'^T + bias. wBh staged through LDS in 16 double-
//          buffered 32KB col-tiles with register prefetch; fragment reads
//          are ds_read_b128 instead of strided L2 gathers.
__global__ __launch_bounds__(BT) void coop_kernel(
    const float* __restrict__ x, const float* __restrict__ wA,
    const float* __restrict__ wB, const float* __restrict__ bias,
    const float* __restrict__ scaleA, const float* __restrict__ scaleB,
    float* __restrict__ out, half_t* __restrict__ wAT, half_t* __restrict__ wBh)
{
    __shared__ __align__(16) char pool[2 * CT * WBS * 2];  // 72 KB (xs | wbs)
    __shared__ __align__(16) half_t xp[TM][XP_STRIDE];     // 4.6 KB

    half_t (*xs)[TM][SXS]  = (half_t(*)[TM][SXS])pool;     // phase A view
    half_t (*wbs)[CT][WBS] = (half_t(*)[CT][WBS])pool;     // phase B view

    int tid = threadIdx.x;
    int bid = blockIdx.x;

    // ---- Phase 0: prep (v2, coalesced) --------------------------------------
    {
        int id = bid * BT + tid;
        if (id < 65536) {
            // wB -> wBh [4096][64], natural layout, 8B stores
            int row = id >> 4;
            int gq  = id & 15;
            float s = scaleB[0];
            f16x4 h = thr4(*(const float4*)(wB + (size_t)row * RANK + gq * 4), s);
            *(f16x4*)(wBh + (size_t)row * RANK + gq * 4) = h;
        } else if (id < 65536 + 8192) {
            // wA -> wAT [64][4096] transposed; thread owns (c4, k8): 8 k x 4 c
            int t2 = id - 65536;
            int c4 = t2 & 15;                      // col group (4 cols)
            int k8 = t2 >> 4;                      // k-run (8 rows of wA)
            float s = scaleA[0];
            f16x8 vc0, vc1, vc2, vc3;
#pragma unroll
            for (int i = 0; i < 8; ++i) {
                float4 v = *(const float4*)(wA + (size_t)(k8 * 8 + i) * RANK + c4 * 4);
                f16x4 h = thr4(v, s);
                vc0[i] = h[0]; vc1[i] = h[1]; vc2[i] = h[2]; vc3[i] = h[3];
            }
            *(f16x8*)(wAT + (size_t)(c4 * 4 + 0) * IN_FEAT + k8 * 8) = vc0;
            *(f16x8*)(wAT + (size_t)(c4 * 4 + 1) * IN_FEAT + k8 * 8) = vc1;
            *(f16x8*)(wAT + (size_t)(c4 * 4 + 2) * IN_FEAT + k8 * 8) = vc2;
            *(f16x8*)(wAT + (size_t)(c4 * 4 + 3) * IN_FEAT + k8 * 8) = vc3;
        }
    }
    cg::this_grid().sync();

    int wave = tid >> 6;                           // 0..7
    int lane = tid & 63;
    int l16  = lane & 15;
    int g    = lane >> 4;
    int rowbase = bid * TM;
    int stripe  = wave & 1;                        // 16-row half
    int quad    = wave >> 1;                       // col quarter

    // ---- Phase A: xp = f16(x_tile) @ wA' ------------------------------------
    {
        int srow = tid >> 4;                       // 0..31
        int sseg = tid & 15;                       // 0..15
        const float* srcrow = x + (size_t)(rowbase + srow) * IN_FEAT + sseg * 4;

        // prologue: stage chunk 0
        {
            const f32x4* p = (const f32x4*)(srcrow);
            f32x4 a0 = p[0], a1 = p[16], a2 = p[32], a3 = p[48];
            half_t* dst = &xs[0][srow][sseg * 4];
            *(f16x4*)(dst +   0) = cvt4(a0);
            *(f16x4*)(dst +  64) = cvt4(a1);
            *(f16x4*)(dst + 128) = cvt4(a2);
            *(f16x4*)(dst + 192) = cvt4(a3);
        }
        __syncthreads();

        f32x4 acc = {0, 0, 0, 0};
        const half_t* wcol = wAT + (size_t)(quad * 16 + l16) * IN_FEAT;
        const half_t* arow = &xs[0][stripe * 16 + l16][0];
        const int xsstep = TM * SXS;
        f32x4 ld0, ld1, ld2, ld3;

        for (int c = 0; c < IN_FEAT / KC2; ++c) {
            if (c + 1 < IN_FEAT / KC2) {           // issue next x-chunk loads
                const f32x4* p = (const f32x4*)(srcrow + (c + 1) * KC2);
                ld0 = p[0]; ld1 = p[16]; ld2 = p[32]; ld3 = p[48];
            }
            // batch ALL 8 wAT fragments (one L2 round-trip per chunk)
            f16x8 bfr[8];
#pragma unroll
            for (int j = 0; j < 8; ++j)
                bfr[j] = *(const f16x8*)(wcol + c * KC2 + j * 32 + 8 * g);

            const half_t* ar = arow + (c & 1) * xsstep;
#pragma unroll
            for (int j = 0; j < 8; ++j) {
                f16x8 a = *(const f16x8*)(ar + j * 32 + 8 * g);
                acc = __builtin_amdgcn_mfma_f32_16x16x32_f16(a, bfr[j], acc, 0, 0, 0);
            }
            if (c + 1 < IN_FEAT / KC2) {
                half_t* dst = &xs[(c + 1) & 1][srow][sseg * 4];
                *(f16x4*)(dst +   0) = cvt4(ld0);
                *(f16x4*)(dst +  64) = cvt4(ld1);
                *(f16x4*)(dst + 128) = cvt4(ld2);
                *(f16x4*)(dst + 192) = cvt4(ld3);
            }
            __syncthreads();
        }

        // C/D: col = lane&15, row = 4*(lane>>4)+reg; full-K f32 -> f16
#pragma unroll
        for (int r = 0; r < 4; ++r)
            xp[stripe * 16 + 4 * g + r][quad * 16 + l16] = (half_t)acc[r];
    }
    __syncthreads();   // xp ready; xs dead -> pool becomes wbs

    // ---- Phase B: out = xp @ wB'^T + bias, LDS-staged wBh -------------------
    {
        // a-fragments (stable across tiles)
        const half_t* xprow = &xp[stripe * 16 + l16][0];
        f16x8 a0 = *(const f16x8*)(xprow + 8 * g);
        f16x8 a1 = *(const f16x8*)(xprow + 32 + 8 * g);

        // staging role: thread -> (col c, half h); 64B contiguous per thread
        int sc = tid >> 1;                         // 0..255
        int sh = tid & 1;                          // 0..1

        // prologue: stage tile 0
        {
            const half_t* src = wBh + 0 * (CT * RANK) + (size_t)sc * RANK + sh * 32;
            f16x8 w0 = *(const f16x8*)(src + 0);
            f16x8 w1 = *(const f16x8*)(src + 8);
            f16x8 w2 = *(const f16x8*)(src + 16);
            f16x8 w3 = *(const f16x8*)(src + 24);
            half_t* dst = &wbs[0][sc][sh * 32];
            *(f16x8*)(dst + 0)  = w0;
            *(f16x8*)(dst + 8)  = w1;
            *(f16x8*)(dst + 16) = w2;
            *(f16x8*)(dst + 24) = w3;
        }
        __syncthreads();

        for (int ct = 0; ct < OUT_FEAT / CT; ++ct) {
            f16x8 p0, p1, p2, p3;
            if (ct + 1 < OUT_FEAT / CT) {          // prefetch next tile
                const half_t* src = wBh + (size_t)(ct + 1) * (CT * RANK)
                                  + (size_t)sc * RANK + sh * 32;
                p0 = *(const f16x8*)(src + 0);
                p1 = *(const f16x8*)(src + 8);
                p2 = *(const f16x8*)(src + 16);
                p3 = *(const f16x8*)(src + 24);
            }

            const int buf = ct & 1;
#pragma unroll
            for (int f = 0; f < 4; ++f) {
                int cl = quad * 64 + 16 * f + l16;
                f16x8 b0 = *(const f16x8*)&wbs[buf][cl][8 * g];
                f16x8 b1 = *(const f16x8*)&wbs[buf][cl][32 + 8 * g];
                f32x4 acc2 = {0, 0, 0, 0};
                acc2 = __builtin_amdgcn_mfma_f32_16x16x32_f16(a0, b0, acc2, 0, 0, 0);
                acc2 = __builtin_amdgcn_mfma_f32_16x16x32_f16(a1, b1, acc2, 0, 0, 0);
                int col = ct * CT + cl;
                float bv = bias[col];
#pragma unroll
                for (int r = 0; r < 4; ++r)
                    out[(size_t)(rowbase + stripe * 16 + 4 * g + r) * OUT_FEAT + col] = acc2[r] + bv;
            }

            if (ct + 1 < OUT_FEAT / CT) {          // commit prefetch to other buf
                half_t* dst = &wbs[(ct + 1) & 1][sc][sh * 32];
                *(f16x8*)(dst + 0)  = p0;
                *(f16x8*)(dst + 8)  = p1;
                *(f16x8*)(dst + 16) = p2;
                *(f16x8*)(dst + 24) = p3;
            }
            __syncthreads();
        }
    }
}

// ===================== fallback: zero-ws fused (round-4, passing) ===========
__global__ __launch_bounds__(256) void fused_kernel(
    const float* __restrict__ x, const float* __restrict__ wA,
    const float* __restrict__ wB, const float* __restrict__ bias,
    const float* __restrict__ scaleA, const float* __restrict__ scaleB,
    float* __restrict__ out)
{
    __shared__ __align__(16) half_t wAsT[RANK][WA_STRIDE];
    __shared__ float xp_part[2][TM][XP_STRIDE];
    __shared__ __align__(16) half_t xp[TM][XP_STRIDE];

    int tid  = threadIdx.x;
    int wave = tid >> 6;
    int lane = tid & 63;
    int l16  = lane & 15;
    int g    = lane >> 4;
    int rowbase = blockIdx.x * TM;
    int stripe  = wave & 1;
    int ks      = wave >> 1;

    float sA = scaleA[0];
    float sB = scaleB[0];

    const float* xrow = x + (size_t)(rowbase + stripe * 16 + l16) * IN_FEAT;
    f32x4 acc[4] = {f32x4{0,0,0,0}, f32x4{0,0,0,0}, f32x4{0,0,0,0}, f32x4{0,0,0,0}};

    for (int chunk = 0; chunk < IN_FEAT / KC; ++chunk) {
        int k0 = chunk * KC;
#pragma unroll
        for (int pp = 0; pp < 2; ++pp) {
            int p = tid + pp * 256;
            int q = p & 15;
            int r = p >> 4;
            f16x8 vc0, vc1, vc2, vc3;
#pragma unroll
            for (int i = 0; i < 8; ++i) {
                float4 v = *(const float4*)(wA + (size_t)(k0 + 8 * r + i) * RANK + 4 * q);
                f16x4 h = thr4(v, sA);
                vc0[i] = h[0]; vc1[i] = h[1]; vc2[i] = h[2]; vc3[i] = h[3];
            }
            *(f16x8*)&wAsT[4 * q + 0][8 * r] = vc0;
            *(f16x8*)&wAsT[4 * q + 1][8 * r] = vc1;
            *(f16x8*)&wAsT[4 * q + 2][8 * r] = vc2;
            *(f16x8*)&wAsT[4 * q + 3][8 * r] = vc3;
        }
        __syncthreads();

#pragma unroll
        for (int it = 0; it < 4; ++it) {
            int kloc = ks * 128 + it * 32;
            float4 xa = *(const float4*)(xrow + k0 + kloc + 8 * g);
            float4 xb = *(const float4*)(xrow + k0 + kloc + 8 * g + 4);
            f16x8 a;
            a[0] = (half_t)xa.x; a[1] = (half_t)xa.y; a[2] = (half_t)xa.z; a[3] = (half_t)xa.w;
            a[4] = (half_t)xb.x; a[5] = (half_t)xb.y; a[6] = (half_t)xb.z; a[7] = (half_t)xb.w;
#pragma unroll
            for (int f = 0; f < 4; ++f) {
                f16x8 b = *(const f16x8*)&wAsT[16 * f + l16][kloc + 8 * g];
                acc[f] = __builtin_amdgcn_mfma_f32_16x16x32_f16(a, b, acc[f], 0, 0, 0);
            }
        }
        __syncthreads();
    }

#pragma unroll
    for (int f = 0; f < 4; ++f)
#pragma unroll
        for (int r = 0; r < 4; ++r)
            xp_part[ks][stripe * 16 + 4 * g + r][16 * f + l16] = acc[f][r];
    __syncthreads();

#pragma unroll
    for (int i = 0; i < (TM * RANK) / 256; ++i) {
        int e = i * 256 + tid;
        int r = e >> 6, c = e & 63;
        xp[r][c] = (half_t)(xp_part[0][r][c] + xp_part[1][r][c]);
    }
    __syncthreads();

    {
        const half_t* xprow = &xp[stripe * 16 + l16][0];
        f16x8 a0 = *(const f16x8*)(xprow + 8 * g);
        f16x8 a1 = *(const f16x8*)(xprow + 32 + 8 * g);

        int cb0 = ks * (OUT_FEAT / 2);
        for (int cb = cb0; cb < cb0 + OUT_FEAT / 2; cb += 16) {
            int col = cb + l16;
            const float* wp = wB + (size_t)col * RANK;
            float4 w00 = *(const float4*)(wp + 8 * g);
            float4 w01 = *(const float4*)(wp + 8 * g + 4);
            float4 w10 = *(const float4*)(wp + 32 + 8 * g);
            float4 w11 = *(const float4*)(wp + 32 + 8 * g + 4);
            f16x4 b00 = thr4(w00, sB), b01 = thr4(w01, sB);
            f16x4 b10 = thr4(w10, sB), b11 = thr4(w11, sB);
            f16x8 b0, b1;
            b0[0]=b00[0]; b0[1]=b00[1]; b0[2]=b00[2]; b0[3]=b00[3];
            b0[4]=b01[0]; b0[5]=b01[1]; b0[6]=b01[2]; b0[7]=b01[3];
            b1[0]=b10[0]; b1[1]=b10[1]; b1[2]=b10[2]; b1[3]=b10[3];
            b1[4]=b11[0]; b1[5]=b11[1]; b1[6]=b11[2]; b1[7]=b11[3];

            f32x4 acc2 = {0, 0, 0, 0};
            acc2 = __builtin_amdgcn_mfma_f32_16x16x32_f16(a0, b0, acc2, 0, 0, 0);
            acc2 = __builtin_amdgcn_mfma_f32_16x16x32_f16(a1, b1, acc2, 0, 0, 0);
            float bv = bias[col];
#pragma unroll
            for (int r = 0; r < 4; ++r)
                out[(size_t)(rowbase + stripe * 16 + 4 * g + r) * OUT_FEAT + col] = acc2[r] + bv;
        }
    }
}

extern "C" void kernel_launch(void* const* d_in, const int* in_sizes, int n_in,
                              void* d_out, int out_size, void* d_ws, size_t ws_size,
                              hipStream_t stream) {
    const float* x      = (const float*)d_in[0];
    const float* wA     = (const float*)d_in[1];
    const float* wB     = (const float*)d_in[2];
    const float* bias   = (const float*)d_in[3];
    const float* scaleA = (const float*)d_in[4];
    const float* scaleB = (const float*)d_in[5];
    float* out = (float*)d_out;

    const size_t WS_NEED = (size_t)RANK * IN_FEAT * 2      // wAT 512 KB
                         + (size_t)OUT_FEAT * RANK * 2;    // wBh 512 KB

    bool launched = false;
    if (ws_size >= WS_NEED && d_ws != nullptr) {
        half_t* wAT = (half_t*)d_ws;
        half_t* wBh = wAT + (size_t)RANK * IN_FEAT;
        void* args[] = {(void*)&x, (void*)&wA, (void*)&wB, (void*)&bias,
                        (void*)&scaleA, (void*)&scaleB, (void*)&out,
                        (void*)&wAT, (void*)&wBh};
        hipError_t err = hipLaunchCooperativeKernel((void*)coop_kernel,
                                                    dim3(NROWS / TM), dim3(BT),
                                                    args, 0, stream);
        launched = (err == hipSuccess);
    }
    if (!launched) {
        fused_kernel<<<NROWS / TM, 256, 0, stream>>>(x, wA, wB, bias, scaleA, scaleB, out);
    }
}